// Round 11
// baseline (442.981 us; speedup 1.0000x reference)
//
#include <hip/hip_runtime.h>
#include <hip/hip_bf16.h>
#include <cstdint>
#include <cstddef>

#define NN 10000
#define MAXDEG 128
#define LDX 384

#define RB_ROWS 80
#define NRB 125
#define SEG2 12
#define COLSCAN_BLKS 1250          // NRB x 10 col-stripes
#define GEMM_BLKS 313

typedef __attribute__((ext_vector_type(8))) short bf16x8;
typedef __attribute__((ext_vector_type(4))) float f32x4;

__device__ __forceinline__ float bf2f(unsigned short u) {
    union { unsigned int i; float f; } c; c.i = ((unsigned int)u) << 16; return c.f;
}
__device__ __forceinline__ unsigned short f2bf(float f) {
    union { float f; unsigned int i; } c; c.f = f;
    unsigned int x = c.i;
    return (unsigned short)((x + 0x7fffu + ((x >> 16) & 1u)) >> 16);
}

// ---- column-owned scan: thread owns 4 adjacent columns; NO LDS ----
// (byte-identical logic to R10 — this round measures it via 3x replication)
__global__ __launch_bounds__(256) void scan_colown(
        const float* __restrict__ A,          // [NN][NN] row-major
        int* __restrict__ csr2,               // [NRB][NN][SEG2]
        int* __restrict__ cnt2) {             // [NN][128]
    int bid = blockIdx.x;
    int t = threadIdx.x;
    if (t >= 250) return;
    int rb  = bid / 10;
    int cbs = bid % 10;
    int r0  = rb * RB_ROWS;
    int c   = cbs * 1000 + t * 4;
    const float4* base = (const float4*)A;
    int idx0 = r0 * (NN / 4) + (c >> 2);

    float4 buf[8];
    #pragma unroll
    for (int d = 0; d < 8; ++d)
        buf[d] = base[idx0 + d * (NN / 4)];

    int n0 = 0, n1 = 0, n2 = 0, n3 = 0;
    size_t segbase = ((size_t)rb * NN + c) * SEG2;

    #pragma unroll 8
    for (int r = 0; r < RB_ROWS; ++r) {
        float4 v = buf[r & 7];
        buf[r & 7] = base[idx0 + min(r + 8, RB_ROWS - 1) * (NN / 4)];
        int row = r0 + r;
        if (v.x != 0.f) { if (n0 < SEG2) csr2[segbase + n0] = row; n0++; }
        if (v.y != 0.f) { if (n1 < SEG2) csr2[segbase + SEG2 + n1] = row; n1++; }
        if (v.z != 0.f) { if (n2 < SEG2) csr2[segbase + 2 * SEG2 + n2] = row; n2++; }
        if (v.w != 0.f) { if (n3 < SEG2) csr2[segbase + 3 * SEG2 + n3] = row; n3++; }
    }
    cnt2[(c + 0) * 128 + rb] = n0;
    cnt2[(c + 1) * 128 + rb] = n1;
    cnt2[(c + 2) * 128 + rb] = n2;
    cnt2[(c + 3) * 128 + rb] = n3;
}

// ---- gemm_in (blocks 0..312) | weight transpose+convert (block 313) ----
__global__ __launch_bounds__(256) void gemm_conv(
        const float* __restrict__ x, const float* __restrict__ W_in,
        const float* __restrict__ b_in,
        const float* __restrict__ W_cheb, const float* __restrict__ W_out,
        unsigned short* __restrict__ Xc,
        unsigned short* __restrict__ Wtc, unsigned short* __restrict__ Wto) {
    __shared__ float smem[5120];   // 20 KB
    int bid = blockIdx.x;
    int t = threadIdx.x;

    if (bid < GEMM_BLKS) {
        constexpr int K = 256, N = 128, BM = 32, KC = 32;
        float* Wl = smem;
        float* Al = smem + KC * N;
        int r0 = bid * BM;
        int c2 = t & 63;
        int g  = t >> 6;
        float2 acc[8];
        #pragma unroll
        for (int i = 0; i < 8; ++i) acc[i] = make_float2(0.f, 0.f);

        for (int kk = 0; kk < K; kk += KC) {
            __syncthreads();
            #pragma unroll
            for (int i = 0; i < KC * N / 4 / 256; ++i) {
                int idx = t + i * 256;
                ((float4*)Wl)[idx] = ((const float4*)(W_in + (size_t)kk * N))[idx];
            }
            {
                int row = t >> 3;
                int cf  = t & 7;
                float4 v = make_float4(0.f, 0.f, 0.f, 0.f);
                if (r0 + row < NN)
                    v = *(const float4*)(x + (size_t)(r0 + row) * K + kk + cf * 4);
                *(float4*)(Al + row * KC + cf * 4) = v;
            }
            __syncthreads();
            for (int k = 0; k < KC; k += 4) {
                float4 av[8];
                #pragma unroll
                for (int rr = 0; rr < 8; ++rr)
                    av[rr] = *(const float4*)(Al + (g * 8 + rr) * KC + k);
                #pragma unroll
                for (int k2 = 0; k2 < 4; ++k2) {
                    float2 wv = *(const float2*)(Wl + (k + k2) * N + c2 * 2);
                    #pragma unroll
                    for (int rr = 0; rr < 8; ++rr) {
                        float a = (k2 == 0) ? av[rr].x : (k2 == 1) ? av[rr].y
                                  : (k2 == 2) ? av[rr].z : av[rr].w;
                        acc[rr].x = fmaf(a, wv.x, acc[rr].x);
                        acc[rr].y = fmaf(a, wv.y, acc[rr].y);
                    }
                }
            }
        }
        float2 bv = *(const float2*)(b_in + c2 * 2);
        #pragma unroll
        for (int rr = 0; rr < 8; ++rr) {
            int r = r0 + g * 8 + rr;
            if (r < NN) {
                float vx = fmaxf(acc[rr].x + bv.x, 0.f);
                float vy = fmaxf(acc[rr].y + bv.y, 0.f);
                uint32_t o = (uint32_t)f2bf(vx) | ((uint32_t)f2bf(vy) << 16);
                *(uint32_t*)(Xc + (size_t)r * LDX + c2 * 2) = o;
            }
        }
    } else {
        for (int idx = t; idx < 384 * 128; idx += 256) {
            int k = idx >> 7, c = idx & 127;
            Wtc[c * 384 + k] = f2bf(W_cheb[idx]);
        }
        for (int idx = t; idx < 128 * 64; idx += 256) {
            int k = idx >> 6, c = idx & 63;
            Wto[c * 128 + k] = f2bf(W_out[idx]);
        }
    }
}

// ---- stitch: concat per-rowblock segments -> csr, compute cnt & norm -------
__global__ __launch_bounds__(256) void stitch_norm(
        const int* __restrict__ csr2, const int* __restrict__ cnt2,
        int* __restrict__ csr, int* __restrict__ cnt, float* __restrict__ nrm) {
    int w = threadIdx.x >> 6, l = threadIdx.x & 63;
    int c = blockIdx.x * 4 + w;
    if (c >= NN) return;

    int a  = (l < NRB)      ? cnt2[c * 128 + l]      : 0;
    int bb = (l + 64 < NRB) ? cnt2[c * 128 + 64 + l] : 0;

    int xa = a, xb = bb;
    #pragma unroll
    for (int d = 1; d < 64; d <<= 1) {
        int ya = __shfl_up(xa, d);
        int yb = __shfl_up(xb, d);
        if (l >= d) { xa += ya; xb += yb; }
    }
    int totalA = __shfl(xa, 63);
    int total  = totalA + __shfl(xb, 63);
    int offA = xa - a;
    int offB = totalA + xb - bb;

    const int* segA = csr2 + ((size_t)l * NN + c) * SEG2;
    for (int e = 0; e < a; ++e) {
        int o = offA + e;
        if (o < MAXDEG) csr[(size_t)c * MAXDEG + o] = segA[e];
    }
    if (l + 64 < NRB) {
        const int* segB = csr2 + ((size_t)(l + 64) * NN + c) * SEG2;
        for (int e = 0; e < bb; ++e) {
            int o = offB + e;
            if (o < MAXDEG) csr[(size_t)c * MAXDEG + o] = segB[e];
        }
    }
    if (l == 0) {
        cnt[c] = min(total, MAXDEG);
        nrm[c] = rsqrtf(fmaxf((float)total, 1.f));
    }
}

// ---------------- sparse propagation (bf16, unroll-4, norm array) -----------
template<bool SUB>
__global__ __launch_bounds__(256) void prop_k(unsigned short* __restrict__ X,
                                              const int* __restrict__ csr,
                                              const int* __restrict__ cnt,
                                              const float* __restrict__ nrm,
                                              int srcOff, int dstOff, float scale) {
    int j = blockIdx.x * 4 + (threadIdx.x >> 6);
    if (j >= NN) return;
    int lane = threadIdx.x & 63;
    int cn = cnt[j];
    const int* nb = csr + (size_t)j * MAXDEG;
    float ax0 = 0.f, ay0 = 0.f, ax1 = 0.f, ay1 = 0.f;
    float ax2 = 0.f, ay2 = 0.f, ax3 = 0.f, ay3 = 0.f;
    int e = 0;
    for (; e + 4 <= cn; e += 4) {
        int i0 = nb[e], i1 = nb[e + 1], i2 = nb[e + 2], i3 = nb[e + 3];
        float w0 = nrm[i0], w1 = nrm[i1], w2 = nrm[i2], w3 = nrm[i3];
        uint32_t h0 = *(const uint32_t*)(X + (size_t)i0 * LDX + srcOff + lane * 2);
        uint32_t h1 = *(const uint32_t*)(X + (size_t)i1 * LDX + srcOff + lane * 2);
        uint32_t h2 = *(const uint32_t*)(X + (size_t)i2 * LDX + srcOff + lane * 2);
        uint32_t h3 = *(const uint32_t*)(X + (size_t)i3 * LDX + srcOff + lane * 2);
        ax0 = fmaf(w0, bf2f((unsigned short)h0), ax0);
        ay0 = fmaf(w0, bf2f((unsigned short)(h0 >> 16)), ay0);
        ax1 = fmaf(w1, bf2f((unsigned short)h1), ax1);
        ay1 = fmaf(w1, bf2f((unsigned short)(h1 >> 16)), ay1);
        ax2 = fmaf(w2, bf2f((unsigned short)h2), ax2);
        ay2 = fmaf(w2, bf2f((unsigned short)(h2 >> 16)), ay2);
        ax3 = fmaf(w3, bf2f((unsigned short)h3), ax3);
        ay3 = fmaf(w3, bf2f((unsigned short)(h3 >> 16)), ay3);
    }
    for (; e < cn; ++e) {
        int i0 = nb[e];
        float w0 = nrm[i0];
        uint32_t h0 = *(const uint32_t*)(X + (size_t)i0 * LDX + srcOff + lane * 2);
        ax0 = fmaf(w0, bf2f((unsigned short)h0), ax0);
        ay0 = fmaf(w0, bf2f((unsigned short)(h0 >> 16)), ay0);
    }
    float s = scale * nrm[j];
    float rx = s * ((ax0 + ax1) + (ax2 + ax3));
    float ry = s * ((ay0 + ay1) + (ay2 + ay3));
    if (SUB) {
        uint32_t x0 = *(const uint32_t*)(X + (size_t)j * LDX + lane * 2);
        rx -= bf2f((unsigned short)x0);
        ry -= bf2f((unsigned short)(x0 >> 16));
    }
    uint32_t o = (uint32_t)f2bf(rx) | ((uint32_t)f2bf(ry) << 16);
    *(uint32_t*)(X + (size_t)j * LDX + dstOff + lane * 2) = o;
}

// -------- MFMA fused: hc = relu(Xc@Wc + bc); out = hc@Wo + bo ---------------
__global__ __launch_bounds__(256) void cheb_out_mfma(
        const unsigned short* __restrict__ Xc,
        const unsigned short* __restrict__ Wtc,
        const float* __restrict__ bc,
        const unsigned short* __restrict__ Wto,
        const float* __restrict__ bo,
        float* __restrict__ out) {
    __shared__ unsigned short hcL[32][136];
    int t = threadIdx.x;
    int w = t >> 6, lane = t & 63;
    int r0 = blockIdx.x * 32;
    int lr = lane & 15;
    int kg = lane >> 4;

    f32x4 acc[2][2] = {};
    for (int k0 = 0; k0 < 384; k0 += 32) {
        bf16x8 a[2], b[2];
        #pragma unroll
        for (int m = 0; m < 2; ++m) {
            int row = r0 + m * 16 + lr;
            row = min(row, NN - 1);
            a[m] = *(const bf16x8*)(Xc + (size_t)row * LDX + k0 + kg * 8);
        }
        #pragma unroll
        for (int n = 0; n < 2; ++n) {
            int col = w * 32 + n * 16 + lr;
            b[n] = *(const bf16x8*)(Wtc + (size_t)col * 384 + k0 + kg * 8);
        }
        #pragma unroll
        for (int m = 0; m < 2; ++m)
            #pragma unroll
            for (int n = 0; n < 2; ++n)
                acc[m][n] = __builtin_amdgcn_mfma_f32_16x16x32_bf16(a[m], b[n], acc[m][n], 0, 0, 0);
    }
    #pragma unroll
    for (int m = 0; m < 2; ++m) {
        #pragma unroll
        for (int n = 0; n < 2; ++n) {
            int col = w * 32 + n * 16 + lr;
            float bv = bc[col];
            #pragma unroll
            for (int r = 0; r < 4; ++r) {
                int row = m * 16 + kg * 4 + r;
                hcL[row][col] = f2bf(fmaxf(acc[m][n][r] + bv, 0.f));
            }
        }
    }
    __syncthreads();
    int rt = w >> 1, ch = w & 1;
    f32x4 a2[2] = {};
    for (int k0 = 0; k0 < 128; k0 += 32) {
        bf16x8 af = *(const bf16x8*)(&hcL[rt * 16 + lr][k0 + kg * 8]);
        #pragma unroll
        for (int n = 0; n < 2; ++n) {
            int col = ch * 32 + n * 16 + lr;
            bf16x8 bf_ = *(const bf16x8*)(Wto + (size_t)col * 128 + k0 + kg * 8);
            a2[n] = __builtin_amdgcn_mfma_f32_16x16x32_bf16(af, bf_, a2[n], 0, 0, 0);
        }
    }
    #pragma unroll
    for (int n = 0; n < 2; ++n) {
        int col = ch * 32 + n * 16 + lr;
        float bv = bo[col];
        #pragma unroll
        for (int r = 0; r < 4; ++r) {
            int row = r0 + rt * 16 + kg * 4 + r;
            if (row < NN) out[(size_t)row * 64 + col] = a2[n][r] + bv;
        }
    }
}

extern "C" void kernel_launch(void* const* d_in, const int* in_sizes, int n_in,
                              void* d_out, int out_size, void* d_ws, size_t ws_size,
                              hipStream_t stream) {
    const float* x      = (const float*)d_in[0];
    const float* adj    = (const float*)d_in[1];
    const float* W_in   = (const float*)d_in[2];
    const float* b_in   = (const float*)d_in[3];
    const float* W_cheb = (const float*)d_in[4];
    const float* b_cheb = (const float*)d_in[5];
    const float* W_out  = (const float*)d_in[6];
    const float* b_out  = (const float*)d_in[7];
    float* out = (float*)d_out;

    char* ws = (char*)d_ws;
    int*            cnt  = (int*)(ws + 0);                     // 40,000 B
    float*          nrm  = (float*)(ws + 65536);               // 40,000 B
    int*            csr  = (int*)(ws + 131072);                // 5.12 MB
    int*            cnt2 = (int*)(ws + 5308416);               // 5.12 MB [NN][128]
    unsigned short* Xc   = (unsigned short*)(ws + 10485760);   // 7.68 MB
    unsigned short* Wtc  = (unsigned short*)(ws + 18874368);   // 98,304 B
    unsigned short* Wto  = (unsigned short*)(ws + 19005440);   // 16,384 B
    int*            csr2 = (int*)(ws + 20971520);              // 60 MB [NRB][NN][12]

    // MEASUREMENT ROUND: scan launched 3x (idempotent — rewrites identical
    // csr2/cnt2 from adj). Delta vs R10 total = 2x in-stream scan cost.
    scan_colown<<<COLSCAN_BLKS, 256, 0, stream>>>(adj, csr2, cnt2);
    scan_colown<<<COLSCAN_BLKS, 256, 0, stream>>>(adj, csr2, cnt2);
    scan_colown<<<COLSCAN_BLKS, 256, 0, stream>>>(adj, csr2, cnt2);
    gemm_conv<<<GEMM_BLKS + 1, 256, 0, stream>>>(x, W_in, b_in, W_cheb, W_out, Xc, Wtc, Wto);
    stitch_norm<<<2500, 256, 0, stream>>>(csr2, cnt2, csr, cnt, nrm);
    prop_k<false><<<(NN + 3) / 4, 256, 0, stream>>>(Xc, csr, cnt, nrm, 0, 128, -1.0f);
    prop_k<true><<<(NN + 3) / 4, 256, 0, stream>>>(Xc, csr, cnt, nrm, 128, 256, -2.0f);
    cheb_out_mfma<<<(NN + 31) / 32, 256, 0, stream>>>(Xc, Wtc, b_cheb, Wto, b_out, out);
}

// Round 13
// 236.361 us; speedup vs baseline: 1.8742x; 1.8742x over previous
//
#include <hip/hip_runtime.h>
#include <hip/hip_bf16.h>
#include <cstdint>
#include <cstddef>

#define NN 10000
#define MAXDEG 128
#define LDX 384

#define RB_ROWS 80
#define NRB 125
#define SEG2 12
#define COLSCAN_BLKS 1250          // NRB x 10 col-stripes
#define GEMM_BLKS 313
#define FATG (COLSCAN_BLKS + GEMM_BLKS + 1)

typedef __attribute__((ext_vector_type(8))) short bf16x8;
typedef __attribute__((ext_vector_type(4))) float f32x4;

__device__ __forceinline__ float bf2f(unsigned short u) {
    union { unsigned int i; float f; } c; c.i = ((unsigned int)u) << 16; return c.f;
}
__device__ __forceinline__ unsigned short f2bf(float f) {
    union { float f; unsigned int i; } c; c.f = f;
    unsigned int x = c.i;
    return (unsigned short)((x + 0x7fffu + ((x >> 16) & 1u)) >> 16);
}

// ---- fat: colscan (0..1249) | gemm_in (1250..1562) | weight convert (1563) -
__global__ __launch_bounds__(256) void fat_scan_gemm(
        const float* __restrict__ A,
        int* __restrict__ csr2, int* __restrict__ cnt2,
        const float* __restrict__ x, const float* __restrict__ W_in,
        const float* __restrict__ b_in,
        const float* __restrict__ W_cheb, const float* __restrict__ W_out,
        unsigned short* __restrict__ Xc,
        unsigned short* __restrict__ Wtc, unsigned short* __restrict__ Wto) {
    __shared__ float smem[5120];   // 20 KB (gemm branch only)
    int bid = blockIdx.x;
    int t = threadIdx.x;

    if (bid < COLSCAN_BLKS) {
        // ---- column-owned scan (byte-identical logic to R10/R11) ----
        if (t >= 250) return;
        int rb  = bid / 10;
        int cbs = bid % 10;
        int r0  = rb * RB_ROWS;
        int c   = cbs * 1000 + t * 4;
        const float4* base = (const float4*)A;
        int idx0 = r0 * (NN / 4) + (c >> 2);

        float4 buf[8];
        #pragma unroll
        for (int d = 0; d < 8; ++d)
            buf[d] = base[idx0 + d * (NN / 4)];

        int n0 = 0, n1 = 0, n2 = 0, n3 = 0;
        size_t segbase = ((size_t)rb * NN + c) * SEG2;

        #pragma unroll 8
        for (int r = 0; r < RB_ROWS; ++r) {
            float4 v = buf[r & 7];
            buf[r & 7] = base[idx0 + min(r + 8, RB_ROWS - 1) * (NN / 4)];
            int row = r0 + r;
            if (v.x != 0.f) { if (n0 < SEG2) csr2[segbase + n0] = row; n0++; }
            if (v.y != 0.f) { if (n1 < SEG2) csr2[segbase + SEG2 + n1] = row; n1++; }
            if (v.z != 0.f) { if (n2 < SEG2) csr2[segbase + 2 * SEG2 + n2] = row; n2++; }
            if (v.w != 0.f) { if (n3 < SEG2) csr2[segbase + 3 * SEG2 + n3] = row; n3++; }
        }
        cnt2[(c + 0) * 128 + rb] = n0;
        cnt2[(c + 1) * 128 + rb] = n1;
        cnt2[(c + 2) * 128 + rb] = n2;
        cnt2[(c + 3) * 128 + rb] = n3;
    } else if (bid < COLSCAN_BLKS + GEMM_BLKS) {
        // ---- gemm_in: X0 = relu(x @ W_in + b_in) -> bf16 Xc[:,0:128] ----
        constexpr int K = 256, N = 128, BM = 32, KC = 32;
        float* Wl = smem;
        float* Al = smem + KC * N;
        int r0 = (bid - COLSCAN_BLKS) * BM;
        int c2 = t & 63;
        int g  = t >> 6;
        float2 acc[8];
        #pragma unroll
        for (int i = 0; i < 8; ++i) acc[i] = make_float2(0.f, 0.f);

        for (int kk = 0; kk < K; kk += KC) {
            __syncthreads();
            #pragma unroll
            for (int i = 0; i < KC * N / 4 / 256; ++i) {
                int idx = t + i * 256;
                ((float4*)Wl)[idx] = ((const float4*)(W_in + (size_t)kk * N))[idx];
            }
            {
                int row = t >> 3;
                int cf  = t & 7;
                float4 v = make_float4(0.f, 0.f, 0.f, 0.f);
                if (r0 + row < NN)
                    v = *(const float4*)(x + (size_t)(r0 + row) * K + kk + cf * 4);
                *(float4*)(Al + row * KC + cf * 4) = v;
            }
            __syncthreads();
            for (int k = 0; k < KC; k += 4) {
                float4 av[8];
                #pragma unroll
                for (int rr = 0; rr < 8; ++rr)
                    av[rr] = *(const float4*)(Al + (g * 8 + rr) * KC + k);
                #pragma unroll
                for (int k2 = 0; k2 < 4; ++k2) {
                    float2 wv = *(const float2*)(Wl + (k + k2) * N + c2 * 2);
                    #pragma unroll
                    for (int rr = 0; rr < 8; ++rr) {
                        float a = (k2 == 0) ? av[rr].x : (k2 == 1) ? av[rr].y
                                  : (k2 == 2) ? av[rr].z : av[rr].w;
                        acc[rr].x = fmaf(a, wv.x, acc[rr].x);
                        acc[rr].y = fmaf(a, wv.y, acc[rr].y);
                    }
                }
            }
        }
        float2 bv = *(const float2*)(b_in + c2 * 2);
        #pragma unroll
        for (int rr = 0; rr < 8; ++rr) {
            int r = r0 + g * 8 + rr;
            if (r < NN) {
                float vx = fmaxf(acc[rr].x + bv.x, 0.f);
                float vy = fmaxf(acc[rr].y + bv.y, 0.f);
                uint32_t o = (uint32_t)f2bf(vx) | ((uint32_t)f2bf(vy) << 16);
                *(uint32_t*)(Xc + (size_t)r * LDX + c2 * 2) = o;
            }
        }
    } else {
        for (int idx = t; idx < 384 * 128; idx += 256) {
            int k = idx >> 7, c = idx & 127;
            Wtc[c * 384 + k] = f2bf(W_cheb[idx]);
        }
        for (int idx = t; idx < 128 * 64; idx += 256) {
            int k = idx >> 6, c = idx & 63;
            Wto[c * 128 + k] = f2bf(W_out[idx]);
        }
    }
}

// ---- nrm_k: per-column degree total -> cnt, nrm ----
// ONLY the NRB=125 valid slots; slots 125..127 are never written (poison!).
__global__ __launch_bounds__(256) void nrm_k(const int* __restrict__ cnt2,
                                             int* __restrict__ cnt,
                                             float* __restrict__ nrm) {
    int j = blockIdx.x * 256 + threadIdx.x;
    if (j >= NN) return;
    const int4* p = (const int4*)(cnt2 + (size_t)j * 128);
    int s = 0;
    #pragma unroll
    for (int k = 0; k < 31; ++k) {    // slots 0..123
        int4 v = p[k];
        s += v.x + v.y + v.z + v.w;
    }
    s += cnt2[(size_t)j * 128 + 124]; // slot 124 (last valid)
    cnt[j] = min(s, MAXDEG);
    nrm[j] = rsqrtf(fmaxf((float)s, 1.f));
}

// ---- fused stitch + prop1: build csr[j] (LDS+global), then X1[j] ----
__global__ __launch_bounds__(256) void stitch_prop1(
        const int* __restrict__ csr2, const int* __restrict__ cnt2,
        const float* __restrict__ nrm,
        int* __restrict__ csr, unsigned short* __restrict__ X) {
    __shared__ int nbL[4][MAXDEG];
    int w = threadIdx.x >> 6, l = threadIdx.x & 63;
    int c = blockIdx.x * 4 + w;     // always < NN (grid=2500, NN=10000)

    int a  = (l < NRB)      ? cnt2[c * 128 + l]      : 0;
    int bb = (l + 64 < NRB) ? cnt2[c * 128 + 64 + l] : 0;

    int xa = a, xb = bb;
    #pragma unroll
    for (int d = 1; d < 64; d <<= 1) {
        int ya = __shfl_up(xa, d);
        int yb = __shfl_up(xb, d);
        if (l >= d) { xa += ya; xb += yb; }
    }
    int totalA = __shfl(xa, 63);
    int total  = totalA + __shfl(xb, 63);
    int offA = xa - a;
    int offB = totalA + xb - bb;

    const int* segA = csr2 + ((size_t)l * NN + c) * SEG2;
    for (int e = 0; e < a; ++e) {
        int o = offA + e;
        if (o < MAXDEG) {
            int v = segA[e];
            nbL[w][o] = v;
            csr[(size_t)c * MAXDEG + o] = v;
        }
    }
    if (l + 64 < NRB) {
        const int* segB = csr2 + ((size_t)(l + 64) * NN + c) * SEG2;
        for (int e = 0; e < bb; ++e) {
            int o = offB + e;
            if (o < MAXDEG) {
                int v = segB[e];
                nbL[w][o] = v;
                csr[(size_t)c * MAXDEG + o] = v;
            }
        }
    }
    __syncthreads();   // LDS stitch visible before prop reads (all 256 arrive)

    // ---- prop1 for node c: X1 = -nrm[c] * sum nrm[i] * X0[i] ----
    int cn = min(total, MAXDEG);
    float ax0 = 0.f, ay0 = 0.f, ax1 = 0.f, ay1 = 0.f;
    float ax2 = 0.f, ay2 = 0.f, ax3 = 0.f, ay3 = 0.f;
    int e = 0;
    for (; e + 4 <= cn; e += 4) {
        int i0 = nbL[w][e], i1 = nbL[w][e + 1], i2 = nbL[w][e + 2], i3 = nbL[w][e + 3];
        float w0 = nrm[i0], w1 = nrm[i1], w2 = nrm[i2], w3 = nrm[i3];
        uint32_t h0 = *(const uint32_t*)(X + (size_t)i0 * LDX + l * 2);
        uint32_t h1 = *(const uint32_t*)(X + (size_t)i1 * LDX + l * 2);
        uint32_t h2 = *(const uint32_t*)(X + (size_t)i2 * LDX + l * 2);
        uint32_t h3 = *(const uint32_t*)(X + (size_t)i3 * LDX + l * 2);
        ax0 = fmaf(w0, bf2f((unsigned short)h0), ax0);
        ay0 = fmaf(w0, bf2f((unsigned short)(h0 >> 16)), ay0);
        ax1 = fmaf(w1, bf2f((unsigned short)h1), ax1);
        ay1 = fmaf(w1, bf2f((unsigned short)(h1 >> 16)), ay1);
        ax2 = fmaf(w2, bf2f((unsigned short)h2), ax2);
        ay2 = fmaf(w2, bf2f((unsigned short)(h2 >> 16)), ay2);
        ax3 = fmaf(w3, bf2f((unsigned short)h3), ax3);
        ay3 = fmaf(w3, bf2f((unsigned short)(h3 >> 16)), ay3);
    }
    for (; e < cn; ++e) {
        int i0 = nbL[w][e];
        float w0 = nrm[i0];
        uint32_t h0 = *(const uint32_t*)(X + (size_t)i0 * LDX + l * 2);
        ax0 = fmaf(w0, bf2f((unsigned short)h0), ax0);
        ay0 = fmaf(w0, bf2f((unsigned short)(h0 >> 16)), ay0);
    }
    float s = -1.0f * nrm[c];
    float rx = s * ((ax0 + ax1) + (ax2 + ax3));
    float ry = s * ((ay0 + ay1) + (ay2 + ay3));
    uint32_t o = (uint32_t)f2bf(rx) | ((uint32_t)f2bf(ry) << 16);
    *(uint32_t*)(X + (size_t)c * LDX + 128 + l * 2) = o;
}

// ---------------- sparse propagation (prop2: X2 = -2*prop(X1) - X0) ---------
template<bool SUB>
__global__ __launch_bounds__(256) void prop_k(unsigned short* __restrict__ X,
                                              const int* __restrict__ csr,
                                              const int* __restrict__ cnt,
                                              const float* __restrict__ nrm,
                                              int srcOff, int dstOff, float scale) {
    int j = blockIdx.x * 4 + (threadIdx.x >> 6);
    if (j >= NN) return;
    int lane = threadIdx.x & 63;
    int cn = cnt[j];
    const int* nb = csr + (size_t)j * MAXDEG;
    float ax0 = 0.f, ay0 = 0.f, ax1 = 0.f, ay1 = 0.f;
    float ax2 = 0.f, ay2 = 0.f, ax3 = 0.f, ay3 = 0.f;
    int e = 0;
    for (; e + 4 <= cn; e += 4) {
        int i0 = nb[e], i1 = nb[e + 1], i2 = nb[e + 2], i3 = nb[e + 3];
        float w0 = nrm[i0], w1 = nrm[i1], w2 = nrm[i2], w3 = nrm[i3];
        uint32_t h0 = *(const uint32_t*)(X + (size_t)i0 * LDX + srcOff + lane * 2);
        uint32_t h1 = *(const uint32_t*)(X + (size_t)i1 * LDX + srcOff + lane * 2);
        uint32_t h2 = *(const uint32_t*)(X + (size_t)i2 * LDX + srcOff + lane * 2);
        uint32_t h3 = *(const uint32_t*)(X + (size_t)i3 * LDX + srcOff + lane * 2);
        ax0 = fmaf(w0, bf2f((unsigned short)h0), ax0);
        ay0 = fmaf(w0, bf2f((unsigned short)(h0 >> 16)), ay0);
        ax1 = fmaf(w1, bf2f((unsigned short)h1), ax1);
        ay1 = fmaf(w1, bf2f((unsigned short)(h1 >> 16)), ay1);
        ax2 = fmaf(w2, bf2f((unsigned short)h2), ax2);
        ay2 = fmaf(w2, bf2f((unsigned short)(h2 >> 16)), ay2);
        ax3 = fmaf(w3, bf2f((unsigned short)h3), ax3);
        ay3 = fmaf(w3, bf2f((unsigned short)(h3 >> 16)), ay3);
    }
    for (; e < cn; ++e) {
        int i0 = nb[e];
        float w0 = nrm[i0];
        uint32_t h0 = *(const uint32_t*)(X + (size_t)i0 * LDX + srcOff + lane * 2);
        ax0 = fmaf(w0, bf2f((unsigned short)h0), ax0);
        ay0 = fmaf(w0, bf2f((unsigned short)(h0 >> 16)), ay0);
    }
    float s = scale * nrm[j];
    float rx = s * ((ax0 + ax1) + (ax2 + ax3));
    float ry = s * ((ay0 + ay1) + (ay2 + ay3));
    if (SUB) {
        uint32_t x0 = *(const uint32_t*)(X + (size_t)j * LDX + lane * 2);
        rx -= bf2f((unsigned short)x0);
        ry -= bf2f((unsigned short)(x0 >> 16));
    }
    uint32_t o = (uint32_t)f2bf(rx) | ((uint32_t)f2bf(ry) << 16);
    *(uint32_t*)(X + (size_t)j * LDX + dstOff + lane * 2) = o;
}

// -------- MFMA fused: hc = relu(Xc@Wc + bc); out = hc@Wo + bo ---------------
__global__ __launch_bounds__(256) void cheb_out_mfma(
        const unsigned short* __restrict__ Xc,
        const unsigned short* __restrict__ Wtc,
        const float* __restrict__ bc,
        const unsigned short* __restrict__ Wto,
        const float* __restrict__ bo,
        float* __restrict__ out) {
    __shared__ unsigned short hcL[32][136];
    int t = threadIdx.x;
    int w = t >> 6, lane = t & 63;
    int r0 = blockIdx.x * 32;
    int lr = lane & 15;
    int kg = lane >> 4;

    f32x4 acc[2][2] = {};
    for (int k0 = 0; k0 < 384; k0 += 32) {
        bf16x8 a[2], b[2];
        #pragma unroll
        for (int m = 0; m < 2; ++m) {
            int row = r0 + m * 16 + lr;
            row = min(row, NN - 1);
            a[m] = *(const bf16x8*)(Xc + (size_t)row * LDX + k0 + kg * 8);
        }
        #pragma unroll
        for (int n = 0; n < 2; ++n) {
            int col = w * 32 + n * 16 + lr;
            b[n] = *(const bf16x8*)(Wtc + (size_t)col * 384 + k0 + kg * 8);
        }
        #pragma unroll
        for (int m = 0; m < 2; ++m)
            #pragma unroll
            for (int n = 0; n < 2; ++n)
                acc[m][n] = __builtin_amdgcn_mfma_f32_16x16x32_bf16(a[m], b[n], acc[m][n], 0, 0, 0);
    }
    #pragma unroll
    for (int m = 0; m < 2; ++m) {
        #pragma unroll
        for (int n = 0; n < 2; ++n) {
            int col = w * 32 + n * 16 + lr;
            float bv = bc[col];
            #pragma unroll
            for (int r = 0; r < 4; ++r) {
                int row = m * 16 + kg * 4 + r;
                hcL[row][col] = f2bf(fmaxf(acc[m][n][r] + bv, 0.f));
            }
        }
    }
    __syncthreads();
    int rt = w >> 1, ch = w & 1;
    f32x4 a2[2] = {};
    for (int k0 = 0; k0 < 128; k0 += 32) {
        bf16x8 af = *(const bf16x8*)(&hcL[rt * 16 + lr][k0 + kg * 8]);
        #pragma unroll
        for (int n = 0; n < 2; ++n) {
            int col = ch * 32 + n * 16 + lr;
            bf16x8 bf_ = *(const bf16x8*)(Wto + (size_t)col * 128 + k0 + kg * 8);
            a2[n] = __builtin_amdgcn_mfma_f32_16x16x32_bf16(af, bf_, a2[n], 0, 0, 0);
        }
    }
    #pragma unroll
    for (int n = 0; n < 2; ++n) {
        int col = ch * 32 + n * 16 + lr;
        float bv = bo[col];
        #pragma unroll
        for (int r = 0; r < 4; ++r) {
            int row = r0 + rt * 16 + kg * 4 + r;
            if (row < NN) out[(size_t)row * 64 + col] = a2[n][r] + bv;
        }
    }
}

extern "C" void kernel_launch(void* const* d_in, const int* in_sizes, int n_in,
                              void* d_out, int out_size, void* d_ws, size_t ws_size,
                              hipStream_t stream) {
    const float* x      = (const float*)d_in[0];
    const float* adj    = (const float*)d_in[1];
    const float* W_in   = (const float*)d_in[2];
    const float* b_in   = (const float*)d_in[3];
    const float* W_cheb = (const float*)d_in[4];
    const float* b_cheb = (const float*)d_in[5];
    const float* W_out  = (const float*)d_in[6];
    const float* b_out  = (const float*)d_in[7];
    float* out = (float*)d_out;

    char* ws = (char*)d_ws;
    int*            cnt  = (int*)(ws + 0);                     // 40,000 B
    float*          nrm  = (float*)(ws + 65536);               // 40,000 B
    int*            csr  = (int*)(ws + 131072);                // 5.12 MB
    int*            cnt2 = (int*)(ws + 5308416);               // 5.12 MB [NN][128]
    unsigned short* Xc   = (unsigned short*)(ws + 10485760);   // 7.68 MB
    unsigned short* Wtc  = (unsigned short*)(ws + 18874368);   // 98,304 B
    unsigned short* Wto  = (unsigned short*)(ws + 19005440);   // 16,384 B
    int*            csr2 = (int*)(ws + 20971520);              // 60 MB [NRB][NN][12]

    fat_scan_gemm<<<FATG, 256, 0, stream>>>(
        adj, csr2, cnt2, x, W_in, b_in, W_cheb, W_out, Xc, Wtc, Wto);
    nrm_k<<<(NN + 255) / 256, 256, 0, stream>>>(cnt2, cnt, nrm);
    stitch_prop1<<<2500, 256, 0, stream>>>(csr2, cnt2, nrm, csr, Xc);
    prop_k<true><<<(NN + 3) / 4, 256, 0, stream>>>(Xc, csr, cnt, nrm, 128, 256, -2.0f);
    cheb_out_mfma<<<(NN + 31) / 32, 256, 0, stream>>>(Xc, Wtc, b_cheb, Wto, b_out, out);
}